// Round 4
// baseline (16389.677 us; speedup 1.0000x reference)
//
#include <hip/hip_runtime.h>
#include <hip/hip_bf16.h>

#define N_NODES 10000
#define N_EDGES 100000
#define WIDTH   64
#define KER_W   1024
#define DEPTH   6
#define E_CHUNK 3125   // 32 chunks; keeps total ws footprint at 255 MB < 256 MiB

typedef __attribute__((ext_vector_type(8))) short short8;
typedef __attribute__((ext_vector_type(4))) float f32x4;
typedef unsigned short u16;
typedef unsigned char u8;

__device__ __forceinline__ float bf2f(u16 u) {
    union { float f; unsigned int i; } v; v.i = ((unsigned int)u) << 16; return v.f;
}
__device__ __forceinline__ u16 f2bf(float f) {
    union { float f; unsigned int i; } v; v.f = f;
    unsigned int x = v.i;
    unsigned int r = (x + 0x7fffu + ((x >> 16) & 1u)) >> 16;
    return (u16)r;
}

// ---------------- one-time weight prep ----------------
// k2T[n*1024+k] = k2w[k*1024+n]  (transposed, bf16)
__global__ void k2_transpose_kernel(const float* __restrict__ k2w, u16* __restrict__ k2T) {
    int idx = blockIdx.x * 256 + threadIdx.x;  // 1024*1024
    int n = idx >> 10, k = idx & 1023;
    k2T[idx] = f2bf(k2w[k * 1024 + n]);
}
// GEMM3 column n = o*64+i equals k3w column i*64+o (so GEMM3 emits ewT[e][o][i]).
// k3pT[n*1024+c] = k3w[c*4096 + (n&63)*64 + (n>>6)]   (transposed + permuted, bf16)
__global__ void k3_permT_kernel(const float* __restrict__ k3w, u16* __restrict__ k3pT) {
    int idx = blockIdx.x * 256 + threadIdx.x;  // 4096*1024
    int n = idx >> 10, c = idx & 1023;
    k3pT[idx] = f2bf(k3w[(size_t)c * 4096 + (n & 63) * 64 + (n >> 6)]);
}
__global__ void b3_permute_kernel(const float* __restrict__ b3, float* __restrict__ b3p) {
    int n = blockIdx.x * 256 + threadIdx.x;  // 4096
    if (n >= 4096) return;
    b3p[n] = b3[(n & 63) * 64 + (n >> 6)];
}

// ---------------- degree ----------------
__global__ void deg_kernel(const int* __restrict__ ei, float* __restrict__ deg) {
    int e = blockIdx.x * 256 + threadIdx.x;
    if (e < N_EDGES) atomicAdd(&deg[ei[N_EDGES + e]], 1.0f);
}

// ---------------- layer 1 (per chunk): h1 = relu(ea @ k1 + b1), bf16 ----------------
__global__ void gemm1_kernel(const float* __restrict__ ea, const float* __restrict__ k1w,
                             const float* __restrict__ k1b, u16* __restrict__ h1, int e0) {
    int idx = blockIdx.x * 256 + threadIdx.x;  // E_CHUNK*1024
    int c = idx & 1023;
    int e = (idx >> 10) + e0;
    float acc = k1b[c];
#pragma unroll
    for (int i = 0; i < 6; i++) acc += ea[e * 6 + i] * k1w[i * 1024 + c];
    h1[idx] = f2bf(fmaxf(acc, 0.0f));
}

// ---------------- bf16 MFMA GEMM: C = act(A[M,1024] @ B + bias), bf16 out ----------------
// B passed TRANSPOSED: BT[n*1024+k]. 64x64 tile, 4 waves, each wave 16 rows.
// All staging loads are 16B vector loads.
template <int NOUT, bool RELU>
__global__ __launch_bounds__(256) void gemm_mfma_kernel(const u16* __restrict__ A,
                                                        const u16* __restrict__ BT,
                                                        const float* __restrict__ bias,
                                                        u16* __restrict__ C, int M) {
    constexpr int K = 1024;
    constexpr int LDT = 40;  // padded LDS stride (u16 elems); 80B keeps 16B alignment
    __shared__ u16 Alds[64 * LDT];
    __shared__ u16 Blds[64 * LDT];  // Blds[n][k]

    const int m0 = blockIdx.x * 64;
    const int n0 = blockIdx.y * 64;
    const int t = threadIdx.x;
    const int lane = t & 63, w = t >> 6;

    f32x4 acc[4];
#pragma unroll
    for (int i = 0; i < 4; i++) acc[i] = (f32x4){0.f, 0.f, 0.f, 0.f};

    // staging map: thread t -> row t>>2, 8-elem k-chunk (t&3)*8
    const int sr = t >> 2, skg = (t & 3) * 8;
    const int mrow = m0 + sr;
    const u16* Aptr = A + (size_t)mrow * K + skg;
    const u16* Bptr = BT + (size_t)(n0 + sr) * K + skg;

    const int fm = lane & 15, q = lane >> 4;

    for (int k0 = 0; k0 < K; k0 += 32) {
        short8 av = {0, 0, 0, 0, 0, 0, 0, 0};
        if (mrow < M) av = *reinterpret_cast<const short8*>(Aptr + k0);
        short8 bv = *reinterpret_cast<const short8*>(Bptr + k0);
        *reinterpret_cast<short8*>(&Alds[sr * LDT + skg]) = av;
        *reinterpret_cast<short8*>(&Blds[sr * LDT + skg]) = bv;

        __syncthreads();

        short8 af = *reinterpret_cast<const short8*>(&Alds[(w * 16 + fm) * LDT + q * 8]);
#pragma unroll
        for (int nt = 0; nt < 4; nt++) {
            short8 bf_ = *reinterpret_cast<const short8*>(&Blds[(nt * 16 + fm) * LDT + q * 8]);
            acc[nt] = __builtin_amdgcn_mfma_f32_16x16x32_bf16(af, bf_, acc[nt], 0, 0, 0);
        }
        __syncthreads();
    }

    // C/D layout: col = lane&15 (n), row = q*4 + r (m)
#pragma unroll
    for (int nt = 0; nt < 4; nt++) {
        int col = n0 + nt * 16 + fm;
        float bsv = bias[col];
#pragma unroll
        for (int r = 0; r < 4; r++) {
            int row = m0 + w * 16 + q * 4 + r;
            if (row < M) {
                float v = acc[nt][r] + bsv;
                if (RELU) v = fmaxf(v, 0.0f);
                C[(size_t)row * NOUT + col] = f2bf(v);
            }
        }
    }
}

// ---------------- z0 = x @ fc1_w + fc1_b ----------------
__global__ void z0_kernel(const float* __restrict__ x, const float* __restrict__ w,
                          const float* __restrict__ b, float* __restrict__ z) {
    int idx = blockIdx.x * 256 + threadIdx.x;  // N*64
    int n = idx >> 6, o = idx & 63;
    z[idx] = x[n] * w[o] + b[o];
}

// ---------------- msg over a chunk: agg[dst] += z[src] @ ew[e] (ewT [e][o][i]) ----------------
__global__ __launch_bounds__(256) void msg_kernel(const int* __restrict__ ei,
                                                  const float* __restrict__ z,
                                                  const u16* __restrict__ ewch,
                                                  float* __restrict__ agg, int e0) {
    int el = blockIdx.x * 4 + (threadIdx.x >> 6);  // local edge in chunk
    if (el >= E_CHUNK) return;
    int lane = threadIdx.x & 63;
    int e = e0 + el;
    int src = ei[e], dst = ei[N_EDGES + e];
    const float* zs = z + (size_t)src * 64;
    const u16* wrow = ewch + (size_t)el * 4096 + lane * 64;
    float acc = 0.f;
#pragma unroll
    for (int g = 0; g < 8; g++) {
        short8 wv = *reinterpret_cast<const short8*>(wrow + g * 8);
#pragma unroll
        for (int j = 0; j < 8; j++) acc += zs[g * 8 + j] * bf2f((u16)wv[j]);
    }
    atomicAdd(&agg[(size_t)dst * 64 + lane], acc);
}

// ---------------- z_new = relu(agg/deg + z @ root_w + conv_b) ----------------
__global__ __launch_bounds__(256) void update_kernel(const float* __restrict__ zin,
                                                     const float* __restrict__ agg,
                                                     const float* __restrict__ deg,
                                                     const float* __restrict__ rootw,
                                                     const float* __restrict__ convb,
                                                     float* __restrict__ zout) {
    int n = blockIdx.x * 4 + (threadIdx.x >> 6);
    int o = threadIdx.x & 63;
    float r = convb[o];
    const float* zr = zin + (size_t)n * 64;
#pragma unroll 8
    for (int i = 0; i < 64; i++) r += zr[i] * rootw[i * 64 + o];
    float d = deg[n];
    d = d < 1.0f ? 1.0f : d;
    float v = agg[(size_t)n * 64 + o] / d + r;
    zout[(size_t)n * 64 + o] = fmaxf(v, 0.0f);
}

// ---------------- out = z @ fc2_w + fc2_b ----------------
__global__ void final_kernel(const float* __restrict__ z, const float* __restrict__ w,
                             const float* __restrict__ b, float* __restrict__ out) {
    int n = blockIdx.x * 256 + threadIdx.x;
    if (n >= N_NODES) return;
    float acc = b[0];
#pragma unroll 8
    for (int o = 0; o < 64; o++) acc += z[(size_t)n * 64 + o] * w[o];
    out[n] = acc;
}

// ---------------- diagnostic: report ws_size via absmax ----------------
__global__ void dbg_kernel(float* __restrict__ out, float val, int n) {
    int i = blockIdx.x * 256 + threadIdx.x;
    if (i < n) out[i] = val;
}

extern "C" void kernel_launch(void* const* d_in, const int* in_sizes, int n_in,
                              void* d_out, int out_size, void* d_ws, size_t ws_size,
                              hipStream_t stream) {
    const float* x     = (const float*)d_in[0];
    const int*   ei    = (const int*)  d_in[1];
    const float* ea    = (const float*)d_in[2];
    const float* fc1w  = (const float*)d_in[3];
    const float* fc1b  = (const float*)d_in[4];
    const float* k1w   = (const float*)d_in[5];
    const float* k1b   = (const float*)d_in[6];
    const float* k2w   = (const float*)d_in[7];
    const float* k2b   = (const float*)d_in[8];
    const float* k3w   = (const float*)d_in[9];
    const float* k3b   = (const float*)d_in[10];
    const float* rootw = (const float*)d_in[11];
    const float* convb = (const float*)d_in[12];
    const float* fc2w  = (const float*)d_in[13];
    const float* fc2b  = (const float*)d_in[14];
    float* out = (float*)d_out;

    // footprint: h2 204.8 + ewch 25.6 + h1ch 6.4 + k2T 2.1 + k3pT 8.4
    //          + b3p + zA/zB/agg 7.7 + deg 0.04  = 255.1 MB  (ws = 256 MiB = 268.4 MB)
    const size_t NEED = 255200000;
    if (ws_size < NEED) {
        dbg_kernel<<<(N_NODES + 255) / 256, 256, 0, stream>>>(out, (float)(ws_size >> 20), N_NODES);
        return;
    }

    char* p = (char*)d_ws;
    auto alloc = [&](size_t bytes) {
        char* r = p;
        p += (bytes + 255) & ~(size_t)255;
        return r;
    };
    u16*   h2   = (u16*)  alloc((size_t)N_EDGES * 1024 * 2);   // 204.8 MB (bf16, full)
    u16*   ewch = (u16*)  alloc((size_t)E_CHUNK * 4096 * 2);   // 25.6 MB
    u16*   h1ch = (u16*)  alloc((size_t)E_CHUNK * 1024 * 2);   // 6.4 MB
    u16*   k2T  = (u16*)  alloc((size_t)1024 * 1024 * 2);
    u16*   k3pT = (u16*)  alloc((size_t)4096 * 1024 * 2);
    float* b3p  = (float*)alloc(4096 * 4);
    float* zA   = (float*)alloc((size_t)N_NODES * 64 * 4);
    float* zB   = (float*)alloc((size_t)N_NODES * 64 * 4);
    float* agg  = (float*)alloc((size_t)N_NODES * 64 * 4);
    float* deg  = (float*)alloc((size_t)N_NODES * 4);

    hipMemsetAsync(deg, 0, (size_t)N_NODES * 4, stream);

    k2_transpose_kernel<<<(1024 * 1024) / 256, 256, 0, stream>>>(k2w, k2T);
    k3_permT_kernel<<<(4096 * 1024) / 256, 256, 0, stream>>>(k3w, k3pT);
    b3_permute_kernel<<<16, 256, 0, stream>>>(k3b, b3p);
    deg_kernel<<<(N_EDGES + 255) / 256, 256, 0, stream>>>(ei, deg);

    // h2 (bf16, full) once: edge_attr is depth-invariant
    for (int e0 = 0; e0 < N_EDGES; e0 += E_CHUNK) {
        gemm1_kernel<<<(E_CHUNK * 1024) / 256, 256, 0, stream>>>(ea, k1w, k1b, h1ch, e0);
        dim3 g2((E_CHUNK + 63) / 64, 1024 / 64);
        gemm_mfma_kernel<1024, true><<<g2, 256, 0, stream>>>(
            h1ch, k2T, k2b, h2 + (size_t)e0 * 1024, E_CHUNK);
    }

    z0_kernel<<<(N_NODES * 64) / 256, 256, 0, stream>>>(x, fc1w, fc1b, zA);

    float* zin = zA;
    float* zout = zB;
    for (int d = 0; d < DEPTH; d++) {
        hipMemsetAsync(agg, 0, (size_t)N_NODES * 64 * 4, stream);
        for (int e0 = 0; e0 < N_EDGES; e0 += E_CHUNK) {
            dim3 g3((E_CHUNK + 63) / 64, 4096 / 64);
            gemm_mfma_kernel<4096, false><<<g3, 256, 0, stream>>>(
                h2 + (size_t)e0 * 1024, k3pT, b3p, ewch, E_CHUNK);
            msg_kernel<<<(E_CHUNK + 3) / 4, 256, 0, stream>>>(ei, zin, ewch, agg, e0);
        }
        update_kernel<<<N_NODES / 4, 256, 0, stream>>>(zin, agg, deg, rootw, convb, zout);
        float* tmp = zin; zin = zout; zout = tmp;
    }

    final_kernel<<<(N_NODES + 255) / 256, 256, 0, stream>>>(zin, fc2w, fc2b, out);
}

// Round 5
// 7544.469 us; speedup vs baseline: 2.1724x; 2.1724x over previous
//
#include <hip/hip_runtime.h>
#include <hip/hip_bf16.h>

#define N_NODES 10000
#define N_EDGES 100000
#define DEPTH   6
#define E_CHUNK 12500   // prep-only chunking (h1 staging); 8 chunks

typedef __attribute__((ext_vector_type(8))) short short8;
typedef __attribute__((ext_vector_type(4))) float f32x4;
typedef unsigned short u16;

__device__ __forceinline__ float bf2f(u16 u) {
    union { float f; unsigned int i; } v; v.i = ((unsigned int)u) << 16; return v.f;
}
__device__ __forceinline__ u16 f2bf(float f) {
    union { float f; unsigned int i; } v; v.f = f;
    unsigned int x = v.i;
    unsigned int r = (x + 0x7fffu + ((x >> 16) & 1u)) >> 16;
    return (u16)r;
}

// async global->LDS, 16B per lane (m97 ladder step: 517->874 TF)
__device__ __forceinline__ void gload_lds16(const void* g, void* s) {
    __builtin_amdgcn_global_load_lds((const __attribute__((address_space(1))) void*)g,
                                     (__attribute__((address_space(3))) void*)s, 16, 0, 0);
}

// ---------------- one-time weight prep ----------------
__global__ void k2_transpose_kernel(const float* __restrict__ k2w, u16* __restrict__ k2T) {
    int idx = blockIdx.x * 256 + threadIdx.x;  // 1024*1024
    int n = idx >> 10, k = idx & 1023;
    k2T[idx] = f2bf(k2w[k * 1024 + n]);
}
// GEMM3 column n = o*64+i takes k3w column i*64+o (emits ewT[e][o][i] directly)
__global__ void k3_permT_kernel(const float* __restrict__ k3w, u16* __restrict__ k3pT) {
    int idx = blockIdx.x * 256 + threadIdx.x;  // 4096*1024
    int n = idx >> 10, c = idx & 1023;
    k3pT[idx] = f2bf(k3w[(size_t)c * 4096 + (n & 63) * 64 + (n >> 6)]);
}
__global__ void b3_permute_kernel(const float* __restrict__ b3, float* __restrict__ b3p) {
    int n = blockIdx.x * 256 + threadIdx.x;  // 4096
    if (n >= 4096) return;
    b3p[n] = b3[(n & 63) * 64 + (n >> 6)];
}

// ---------------- degree ----------------
__global__ void deg_kernel(const int* __restrict__ ei, float* __restrict__ deg) {
    int e = blockIdx.x * 256 + threadIdx.x;
    if (e < N_EDGES) atomicAdd(&deg[ei[N_EDGES + e]], 1.0f);
}

// ---------------- layer 1 (per chunk): h1 = relu(ea @ k1 + b1), bf16 ----------------
__global__ void gemm1_kernel(const float* __restrict__ ea, const float* __restrict__ k1w,
                             const float* __restrict__ k1b, u16* __restrict__ h1, int e0) {
    int idx = blockIdx.x * 256 + threadIdx.x;  // E_CHUNK*1024
    int c = idx & 1023;
    int e = (idx >> 10) + e0;
    float acc = k1b[c];
#pragma unroll
    for (int i = 0; i < 6; i++) acc += ea[e * 6 + i] * k1w[i * 1024 + c];
    h1[idx] = f2bf(fmaxf(acc, 0.0f));
}

// ---------------- 128x128-tile bf16 MFMA GEMM, K=1024, global_load_lds staging ----
// A[M][1024] bf16 (rows clamped for staging, masked in epilogue); BT[NOUT][1024] bf16.
// FUSE_MSG=false: C[row][col] = f2bf(acc + bias) (optional relu).
// FUSE_MSG=true (NOUT==4096, C unused): per 128-col n-tile = 2 complete o-rows of
//   ewT[e][o][i]; epilogue reduces msg[e][o] = sum_i (ew+b)*z[src,i] via 16-lane
//   shuffle (cols of the fm-group span i=0..63 at fixed rows) -> atomicAdd agg.
template <int NOUT, bool RELU, bool FUSE_MSG>
__global__ __launch_bounds__(256) void gemm128_kernel(
    const u16* __restrict__ A, const u16* __restrict__ BT,
    const float* __restrict__ bias, u16* __restrict__ C, int M,
    const int* __restrict__ ei, const float* __restrict__ z,
    float* __restrict__ agg) {
    constexpr int K = 1024;
    __shared__ __align__(16) u16 Alds[128 * 32];
    __shared__ __align__(16) u16 Blds[128 * 32];

    const int t = threadIdx.x;
    const int lane = t & 63, w = t >> 6;
    const int wm = w >> 1, wn = w & 1;
    const int fm = lane & 15, q = lane >> 4;
    const int m0 = blockIdx.y * 128;   // rows (edges); y = m-tiles
    const int n0 = blockIdx.x * 128;   // cols; x = n-tiles (fastest-varying for B reuse)

    f32x4 acc[4][4];
#pragma unroll
    for (int a = 0; a < 4; a++)
#pragma unroll
        for (int b = 0; b < 4; b++) acc[a][b] = (f32x4){0.f, 0.f, 0.f, 0.f};

    // staging: round r in {0,1}: row_in_tile = r*64 + t/4, k-offset (t&3)*8
    int ar0 = m0 + (t >> 2);        if (ar0 >= M) ar0 = M - 1;
    int ar1 = m0 + 64 + (t >> 2);   if (ar1 >= M) ar1 = M - 1;
    const u16* gA0 = A + (size_t)ar0 * K + (t & 3) * 8;
    const u16* gA1 = A + (size_t)ar1 * K + (t & 3) * 8;
    const u16* gB0 = BT + (size_t)(n0 + (t >> 2)) * K + (t & 3) * 8;
    const u16* gB1 = BT + (size_t)(n0 + 64 + (t >> 2)) * K + (t & 3) * 8;
    u16* lA0 = &Alds[t * 8];
    u16* lA1 = &Alds[2048 + t * 8];
    u16* lB0 = &Blds[t * 8];
    u16* lB1 = &Blds[2048 + t * 8];

    for (int k0 = 0; k0 < K; k0 += 32) {
        gload_lds16(gA0 + k0, lA0);
        gload_lds16(gA1 + k0, lA1);
        gload_lds16(gB0 + k0, lB0);
        gload_lds16(gB1 + k0, lB1);
        __syncthreads();

        short8 af[4], bf[4];
#pragma unroll
        for (int mi = 0; mi < 4; mi++)
            af[mi] = *reinterpret_cast<const short8*>(&Alds[(wm * 64 + mi * 16 + fm) * 32 + q * 8]);
#pragma unroll
        for (int ni = 0; ni < 4; ni++)
            bf[ni] = *reinterpret_cast<const short8*>(&Blds[(wn * 64 + ni * 16 + fm) * 32 + q * 8]);
#pragma unroll
        for (int mi = 0; mi < 4; mi++)
#pragma unroll
            for (int ni = 0; ni < 4; ni++)
                acc[mi][ni] = __builtin_amdgcn_mfma_f32_16x16x32_bf16(af[mi], bf[ni], acc[mi][ni], 0, 0, 0);
        __syncthreads();
    }

    if (!FUSE_MSG) {
#pragma unroll
        for (int mi = 0; mi < 4; mi++) {
#pragma unroll
            for (int ni = 0; ni < 4; ni++) {
                int col = n0 + wn * 64 + ni * 16 + fm;
                float bsv = bias[col];
#pragma unroll
                for (int r = 0; r < 4; r++) {
                    int row = m0 + wm * 64 + mi * 16 + q * 4 + r;
                    if (row < M) {
                        float v = acc[mi][ni][r] + bsv;
                        if (RELU) v = fmaxf(v, 0.0f);
                        C[(size_t)row * NOUT + col] = f2bf(v);
                    }
                }
            }
        }
    } else {
        const int o = (n0 >> 6) + wn;  // global o index, [0,64)
        float bsv[4];
        int iidx[4];
#pragma unroll
        for (int ni = 0; ni < 4; ni++) {
            bsv[ni] = bias[n0 + wn * 64 + ni * 16 + fm];
            iidx[ni] = ni * 16 + fm;
        }
#pragma unroll
        for (int mi = 0; mi < 4; mi++) {
#pragma unroll
            for (int r = 0; r < 4; r++) {
                int e = m0 + wm * 64 + mi * 16 + q * 4 + r;  // uniform across fm-group
                float partial = 0.f;
                int dst = 0;
                if (e < M) {
                    int src = ei[e];
                    dst = ei[N_EDGES + e];
                    const float* zs = z + (size_t)src * 64;
#pragma unroll
                    for (int ni = 0; ni < 4; ni++)
                        partial += (acc[mi][ni][r] + bsv[ni]) * zs[iidx[ni]];
                }
                partial += __shfl_xor(partial, 1);
                partial += __shfl_xor(partial, 2);
                partial += __shfl_xor(partial, 4);
                partial += __shfl_xor(partial, 8);
                if (fm == 0 && e < M) atomicAdd(&agg[(size_t)dst * 64 + o], partial);
            }
        }
    }
}

// ---------------- z0 = x @ fc1_w + fc1_b ----------------
__global__ void z0_kernel(const float* __restrict__ x, const float* __restrict__ w,
                          const float* __restrict__ b, float* __restrict__ z) {
    int idx = blockIdx.x * 256 + threadIdx.x;  // N*64
    int n = idx >> 6, o = idx & 63;
    z[idx] = x[n] * w[o] + b[o];
}

// ---------------- z_new = relu(agg/deg + z @ root_w + conv_b) ----------------
__global__ __launch_bounds__(256) void update_kernel(const float* __restrict__ zin,
                                                     const float* __restrict__ agg,
                                                     const float* __restrict__ deg,
                                                     const float* __restrict__ rootw,
                                                     const float* __restrict__ convb,
                                                     float* __restrict__ zout) {
    int n = blockIdx.x * 4 + (threadIdx.x >> 6);
    int o = threadIdx.x & 63;
    float r = convb[o];
    const float* zr = zin + (size_t)n * 64;
#pragma unroll 8
    for (int i = 0; i < 64; i++) r += zr[i] * rootw[i * 64 + o];
    float d = deg[n];
    d = d < 1.0f ? 1.0f : d;
    float v = agg[(size_t)n * 64 + o] / d + r;
    zout[(size_t)n * 64 + o] = fmaxf(v, 0.0f);
}

// ---------------- out = z @ fc2_w + fc2_b ----------------
__global__ void final_kernel(const float* __restrict__ z, const float* __restrict__ w,
                             const float* __restrict__ b, float* __restrict__ out) {
    int n = blockIdx.x * 256 + threadIdx.x;
    if (n >= N_NODES) return;
    float acc = b[0];
#pragma unroll 8
    for (int o = 0; o < 64; o++) acc += z[(size_t)n * 64 + o] * w[o];
    out[n] = acc;
}

// ---------------- diagnostic ----------------
__global__ void dbg_kernel(float* __restrict__ out, float val, int n) {
    int i = blockIdx.x * 256 + threadIdx.x;
    if (i < n) out[i] = val;
}

extern "C" void kernel_launch(void* const* d_in, const int* in_sizes, int n_in,
                              void* d_out, int out_size, void* d_ws, size_t ws_size,
                              hipStream_t stream) {
    const float* x     = (const float*)d_in[0];
    const int*   ei    = (const int*)  d_in[1];
    const float* ea    = (const float*)d_in[2];
    const float* fc1w  = (const float*)d_in[3];
    const float* fc1b  = (const float*)d_in[4];
    const float* k1w   = (const float*)d_in[5];
    const float* k1b   = (const float*)d_in[6];
    const float* k2w   = (const float*)d_in[7];
    const float* k2b   = (const float*)d_in[8];
    const float* k3w   = (const float*)d_in[9];
    const float* k3b   = (const float*)d_in[10];
    const float* rootw = (const float*)d_in[11];
    const float* convb = (const float*)d_in[12];
    const float* fc2w  = (const float*)d_in[13];
    const float* fc2b  = (const float*)d_in[14];
    float* out = (float*)d_out;

    // h2 204.8 + h1ch 25.6 + k2T 2.1 + k3pT 8.4 + b3p + zA/zB/agg 7.7 + deg 0.04
    // = 248.7 MB < 268.4 MB (ws = 256 MiB)
    const size_t NEED = 249000000;
    if (ws_size < NEED) {
        dbg_kernel<<<(N_NODES + 255) / 256, 256, 0, stream>>>(out, (float)(ws_size >> 20), N_NODES);
        return;
    }

    char* p = (char*)d_ws;
    auto alloc = [&](size_t bytes) {
        char* r = p;
        p += (bytes + 255) & ~(size_t)255;
        return r;
    };
    u16*   h2   = (u16*)  alloc((size_t)N_EDGES * 1024 * 2);   // 204.8 MB (bf16, L3-resident)
    u16*   h1ch = (u16*)  alloc((size_t)E_CHUNK * 1024 * 2);   // 25.6 MB (prep only)
    u16*   k2T  = (u16*)  alloc((size_t)1024 * 1024 * 2);
    u16*   k3pT = (u16*)  alloc((size_t)4096 * 1024 * 2);
    float* b3p  = (float*)alloc(4096 * 4);
    float* zA   = (float*)alloc((size_t)N_NODES * 64 * 4);
    float* zB   = (float*)alloc((size_t)N_NODES * 64 * 4);
    float* agg  = (float*)alloc((size_t)N_NODES * 64 * 4);
    float* deg  = (float*)alloc((size_t)N_NODES * 4);

    hipMemsetAsync(deg, 0, (size_t)N_NODES * 4, stream);

    k2_transpose_kernel<<<(1024 * 1024) / 256, 256, 0, stream>>>(k2w, k2T);
    k3_permT_kernel<<<(4096 * 1024) / 256, 256, 0, stream>>>(k3w, k3pT);
    b3_permute_kernel<<<16, 256, 0, stream>>>(k3b, b3p);
    deg_kernel<<<(N_EDGES + 255) / 256, 256, 0, stream>>>(ei, deg);

    // h2 = relu(relu(ea@k1+b1)@k2+b2), bf16, once (edge_attr depth-invariant)
    for (int e0 = 0; e0 < N_EDGES; e0 += E_CHUNK) {
        gemm1_kernel<<<(E_CHUNK * 1024) / 256, 256, 0, stream>>>(ea, k1w, k1b, h1ch, e0);
        dim3 g2(1024 / 128, (E_CHUNK + 127) / 128);
        gemm128_kernel<1024, true, false><<<g2, 256, 0, stream>>>(
            h1ch, k2T, k2b, h2 + (size_t)e0 * 1024, E_CHUNK, nullptr, nullptr, nullptr);
    }

    z0_kernel<<<(N_NODES * 64) / 256, 256, 0, stream>>>(x, fc1w, fc1b, zA);

    float* zin = zA;
    float* zout = zB;
    for (int d = 0; d < DEPTH; d++) {
        hipMemsetAsync(agg, 0, (size_t)N_NODES * 64 * 4, stream);
        // fused: ew = h2@k3p (+b3p) and agg[dst] += z[src]@ew, no ew materialization
        dim3 g3(4096 / 128, (N_EDGES + 127) / 128);
        gemm128_kernel<4096, false, true><<<g3, 256, 0, stream>>>(
            h2, k3pT, b3p, nullptr, N_EDGES, ei, zin, agg);
        update_kernel<<<N_NODES / 4, 256, 0, stream>>>(zin, agg, deg, rootw, convb, zout);
        float* tmp = zin; zin = zout; zout = tmp;
    }

    final_kernel<<<(N_NODES + 255) / 256, 256, 0, stream>>>(zin, fc2w, fc2b, out);
}